// Round 2
// baseline (194.691 us; speedup 1.0000x reference)
//
#include <hip/hip_runtime.h>

// Median filter (k=22, REFLECT) + blend, NHWC (2,224,224,3) fp32.
// One wave per 8 consecutive-x pixels, processed as 4 pairs in lockstep.
// Window (484) in 8 regs/lane; ballot counting. V3 (= V2 with the inline-asm
// mask-fold removed — LLVM put ballot masks in VGPR pairs, invalid for
// v_cndmask):
//  - probes drive count to EXACT rank (d==0) with a constant-slope Newton
//    step (density of uniform[0,1) window ~= AREA), bracket+bisection kept
//    only as a termination guarantee;
//  - on exact hit, median = max{v < t}: fold by re-compare (v_cmp+v_cndmask,
//    2 VALU/reg), then one shared A/B butterfly (ds_swizzle imm XOR patterns
//    + one ds_bpermute xor32 — zero per-stage address VALU);
//  - ties at the median (REFLECT duplicates) leave d!=0 -> rare fallback to
//    the proven sign-folded max-peel. Exact for any input.

#define HH 224
#define WW 224
#define CHN 3
#define KK 22
#define PT 10            // pad top/left; bottom/right = 11
#define AREA (KK * KK)   // 484
#define RANK 242         // median = 242nd smallest (1-indexed)
#define PXW 8
#define XGS (WW / PXW)   // 28

#define INFF  __int_as_float(0x7f800000)
#define NINFF __int_as_float(0xff800000)

__device__ __forceinline__ int reflect224(int g) {
    int a = abs(g);
    return min(a, 2 * (HH - 1) - a);
}

__device__ __forceinline__ int count8(const float v[8], float t) {
    int c = 0;
#pragma unroll
    for (int i = 0; i < 8; ++i)
        c += __popcll(__ballot(v[i] < t));
    return c;
}

// butterfly max within each 32-lane half (ds_swizzle BitMode XOR patterns:
// offset = (xor<<10) | 0x1F, no address VALU). Lanes 0-31 and 32-63 reduce
// independently -> supports packed A/B reduce.
__device__ __forceinline__ float half_bfly(float m) {
    m = fmaxf(m, __int_as_float(__builtin_amdgcn_ds_swizzle(__float_as_int(m), 0x401F))); // ^16
    m = fmaxf(m, __int_as_float(__builtin_amdgcn_ds_swizzle(__float_as_int(m), 0x201F))); // ^8
    m = fmaxf(m, __int_as_float(__builtin_amdgcn_ds_swizzle(__float_as_int(m), 0x101F))); // ^4
    m = fmaxf(m, __int_as_float(__builtin_amdgcn_ds_swizzle(__float_as_int(m), 0x081F))); // ^2
    m = fmaxf(m, __int_as_float(__builtin_amdgcn_ds_swizzle(__float_as_int(m), 0x041F))); // ^1
    return m;
}

// fold members (v < t -> keep, else -inf) + in-lane tree max.
// compiler emits v_cmp + v_cndmask(vcc): 2 VALU per reg.
__device__ __forceinline__ float foldtree(const float v[8], float t, float ninf) {
    float s[8];
#pragma unroll
    for (int i = 0; i < 8; ++i)
        s[i] = (v[i] < t) ? v[i] : ninf;
    return fmaxf(fmaxf(fmaxf(s[0], s[1]), fmaxf(s[2], s[3])),
                 fmaxf(fmaxf(s[4], s[5]), fmaxf(s[6], s[7])));
}

// full 64-lane max from per-lane partials: xor32 via ds_bpermute (hoisted
// addr) + half butterfly. All lanes end with the wave max.
__device__ __forceinline__ float wavemax(float s, int axor32) {
    s = fmaxf(s, __int_as_float(
            __builtin_amdgcn_ds_bpermute(axor32, __float_as_int(s))));
    return half_bfly(s);
}

// Fallback: sign-folded bounded max-peel (exact for ties/degenerate brackets).
// top side (d>=0): need (d+1)-th largest of {v<t};  bottom: (-d)-th smallest
// of {v>=t} == peel max of -v. Destroys v. Returns wave-uniform median.
__device__ __forceinline__ float peel1(float v[8], float t, int d, int axor32) {
    const bool top = (d >= 0);
    int e = top ? d + 1 : -d;
    const int sgn = top ? 0 : (int)0x80000000;
#pragma unroll
    for (int i = 0; i < 8; ++i) {
        bool lt = v[i] < t;
        float s = __int_as_float(__float_as_int(v[i]) ^ sgn);
        v[i] = (lt == top) ? s : NINFF;
    }
    float med = t;   // provably overwritten (e <= #candidates)
#pragma unroll 1
    for (int r = 0; r < 300; ++r) {
        float m = fmaxf(fmaxf(fmaxf(v[0], v[1]), fmaxf(v[2], v[3])),
                        fmaxf(fmaxf(v[4], v[5]), fmaxf(v[6], v[7])));
        m = wavemax(m, axor32);
        int q = 0;
#pragma unroll
        for (int i = 0; i < 8; ++i)
            q += __popcll(__ballot(v[i] == m));
        if (e <= q) { med = __int_as_float(__float_as_int(m) ^ sgn); break; }
        e -= q;
#pragma unroll
        for (int i = 0; i < 8; ++i)
            v[i] = (v[i] == m) ? NINFF : v[i];
    }
    return med;
}

__device__ __forceinline__ void gather(float v[8], const float* __restrict__ img,
                                       const int voff[8], int lane, int x) {
    if (x >= PT && x <= WW - 1 - (KK - 1 - PT)) {      // interior: x in [10,212]
        const float* base = img + (x - PT) * CHN;      // wave-uniform base
#pragma unroll
        for (int i = 0; i < 8; ++i) v[i] = base[voff[i]];
    } else {
#pragma unroll
        for (int i = 0; i < 8; ++i) {
            int s   = i * 64 + lane;
            int se  = min(s, AREA - 1);
            int row = se / KK;
            int col = se - row * KK;
            int gy672 = voff[i] - col * CHN;
            int gx = reflect224(x - PT + col);
            v[i] = img[gy672 + gx * CHN];
        }
    }
    v[7] = (lane < AREA - 448) ? v[7] : INFF;          // slots >= 484 -> +INF
}

__global__ __launch_bounds__(256)
void median_blend_kernel(const float* __restrict__ in,
                         const float* __restrict__ blend,
                         float* __restrict__ out) {
    const int lane = threadIdx.x & 63;
    const int wid  = threadIdx.x >> 6;
    const int wg = blockIdx.x * 4 + wid;        // wave-uniform group id
    // wg = ((b*CHN + c)*HH + y)*XGS + xg
    const int xg = wg % XGS;
    const int t1 = wg / XGS;
    const int y  = t1 % HH;
    const int t2 = t1 / HH;
    const int c  = t2 % CHN;
    const int b  = t2 / CHN;

    const float f = blend[0];
    const float* img  = in  + (size_t)b * (HH * WW * CHN) + c;
    float*       outp = out + (size_t)b * (HH * WW * CHN) + c;

    // per-wave lane constants: voff = gy*672 + col*3 (vertical reflect baked in)
    int voff[8];
#pragma unroll
    for (int i = 0; i < 8; ++i) {
        int s   = i * 64 + lane;
        int se  = min(s, AREA - 1);
        int row = se / KK;
        int col = se - row * KK;
        int gy  = reflect224(y - PT + row);
        voff[i] = gy * (WW * CHN) + col * CHN;
    }

    const int axor32 = (lane ^ 32) << 2;        // hoisted bpermute byte addr
    const float ninf = NINFF;
    const float NINV = -1.0f / (float)AREA;     // Newton slope: -1/484

    const int x0 = xg * PXW;
    float tprev = 0.5f;

#pragma unroll 1
    for (int j = 0; j < PXW; j += 2) {
        const int xA = x0 + j;
        const int xB = xA + 1;

        float vA[8], vB[8];
        gather(vA, img, voff, lane, xA);
        gather(vB, img, voff, lane, xB);

        // ---- warm-started Newton probes to EXACT rank, pair in lockstep ----
        float tA = tprev, tB = tprev;
        int CA = count8(vA, tA);
        int CB = count8(vB, tB);
        int dA = CA - RANK, dB = CB - RANK;
        float loA = 0.0f, hiA = 1.0f, loB = 0.0f, hiB = 1.0f;
        bool actA = (dA != 0), actB = (dB != 0);
#pragma unroll 1
        for (int it = 0; it < 20 && (actA || actB); ++it) {
            if (actA) {
                if (dA > 0) hiA = tA; else loA = tA;
                float tn = fmaf((float)dA, NINV, tA);
                if (!(tn > loA && tn < hiA)) tn = 0.5f * (loA + hiA);
                if (!(tn > loA && tn < hiA)) actA = false;   // degenerate (tie)
                else {
                    tA = tn;
                    CA = count8(vA, tA);
                    dA = CA - RANK;
                    actA = (dA != 0);
                }
            }
            if (actB) {
                if (dB > 0) hiB = tB; else loB = tB;
                float tn = fmaf((float)dB, NINV, tB);
                if (!(tn > loB && tn < hiB)) tn = 0.5f * (loB + hiB);
                if (!(tn > loB && tn < hiB)) actB = false;   // degenerate (tie)
                else {
                    tB = tn;
                    CB = count8(vB, tB);
                    dB = CB - RANK;
                    actB = (dB != 0);
                }
            }
        }

        // ---- extraction ----
        // exact hit: median = max{v < t} (exactly RANK values below t).
        float medA, medBall;
        if (dA == 0 && dB == 0) {               // common path: shared reduce
            float sA = foldtree(vA, tA, ninf);
            float sB = foldtree(vB, tB, ninf);
            // xor32 combine per pixel, then pack A->lanes 0-31, B->lanes 32-63
            sA = fmaxf(sA, __int_as_float(
                    __builtin_amdgcn_ds_bpermute(axor32, __float_as_int(sA))));
            sB = fmaxf(sB, __int_as_float(
                    __builtin_amdgcn_ds_bpermute(axor32, __float_as_int(sB))));
            float m = (lane < 32) ? sA : sB;
            m = half_bfly(m);
            medA = m;                            // valid in lanes 0-31 (store: lane 0)
            medBall = __int_as_float(
                __builtin_amdgcn_readlane(__float_as_int(m), 32));
        } else {                                 // rare: tie / slow convergence
            medA = (dA == 0) ? wavemax(foldtree(vA, tA, ninf), axor32)
                             : peel1(vA, tA, dA, axor32);
            medBall = (dB == 0) ? wavemax(foldtree(vB, tB, ninf), axor32)
                                : peel1(vB, tB, dB, axor32);
        }
        tprev = medBall;                         // warm start for next pair

        // ---- blend + store ----
        const float xcA = img[y * (WW * CHN) + xA * CHN];
        const float xcB = img[y * (WW * CHN) + xB * CHN];
        if (lane == 0) {
            outp[y * (WW * CHN) + xA * CHN] = medA + f * (xcA - medA);
            outp[y * (WW * CHN) + xB * CHN] = medBall + f * (xcB - medBall);
        }
    }
}

extern "C" void kernel_launch(void* const* d_in, const int* in_sizes, int n_in,
                              void* d_out, int out_size, void* d_ws, size_t ws_size,
                              hipStream_t stream) {
    const float* in    = (const float*)d_in[0];
    const float* blend = (const float*)d_in[1];
    float* out = (float*)d_out;

    const int nwaves  = 2 * CHN * HH * XGS;   // 37632
    const int nblocks = nwaves / 4;           // 9408
    median_blend_kernel<<<nblocks, 256, 0, stream>>>(in, blend, out);
}

// Round 3
// 153.633 us; speedup vs baseline: 1.2673x; 1.2673x over previous
//
#include <hip/hip_runtime.h>

// Median filter (k=22, REFLECT) + blend, NHWC (2,224,224,3) fp32.
// One wave per 8 consecutive-x pixels, processed as 4 pairs in lockstep.
// Window (484) in 8 regs/lane; ballot counting.
// V4 = V1's proven probe/peel semantics + V3's proven cheap reduce plumbing:
//  - warm-started Newton probes (constant slope -1/AREA, bracket+bisection
//    guard) stop at |count-RANK| <= DT=2  (V1-proven ~3 probes; no exact-hit
//    random walk — that was V3's regression);
//  - extraction: pair-packed q-counting sign-folded max-peel. Per round:
//    in-lane tree + bpermute-xor32 combine + ONE shared 5-stage ds_swizzle
//    butterfly (A in lanes 0-31, B in 32-63, imm XOR patterns = zero address
//    VALU) + readlane broadcast + 8 eq-ballots + 8 purges per active pixel.
//    Rounds <= DT+1 typically; exact for ties/degenerate brackets (q-count).
// Exact for any input incl. REFLECT duplicates; proven cross-lane ops only.

#define HH 224
#define WW 224
#define CHN 3
#define KK 22
#define PT 10            // pad top/left; bottom/right = 11
#define AREA (KK * KK)   // 484
#define RANK 242         // median = 242nd smallest (1-indexed)
#define PXW 8
#define XGS (WW / PXW)   // 28
#define DT 2             // stop probing when |count-RANK| <= DT

#define INFF  __int_as_float(0x7f800000)
#define NINFF __int_as_float(0xff800000)

__device__ __forceinline__ int reflect224(int g) {
    int a = abs(g);
    return min(a, 2 * (HH - 1) - a);
}

__device__ __forceinline__ int count8(const float v[8], float t) {
    int c = 0;
#pragma unroll
    for (int i = 0; i < 8; ++i)
        c += __popcll(__ballot(v[i] < t));
    return c;
}

// in-lane tree max over the 8 window regs
__device__ __forceinline__ float tree8(const float v[8]) {
    return fmaxf(fmaxf(fmaxf(v[0], v[1]), fmaxf(v[2], v[3])),
                 fmaxf(fmaxf(v[4], v[5]), fmaxf(v[6], v[7])));
}

// butterfly max within each 32-lane half (ds_swizzle BitMode XOR patterns:
// offset = (xor<<10) | 0x1F, no address VALU). Lanes 0-31 and 32-63 reduce
// independently -> supports packed A/B reduce.   [proven in V3, absmax 0]
__device__ __forceinline__ float half_bfly(float m) {
    m = fmaxf(m, __int_as_float(__builtin_amdgcn_ds_swizzle(__float_as_int(m), 0x401F))); // ^16
    m = fmaxf(m, __int_as_float(__builtin_amdgcn_ds_swizzle(__float_as_int(m), 0x201F))); // ^8
    m = fmaxf(m, __int_as_float(__builtin_amdgcn_ds_swizzle(__float_as_int(m), 0x101F))); // ^4
    m = fmaxf(m, __int_as_float(__builtin_amdgcn_ds_swizzle(__float_as_int(m), 0x081F))); // ^2
    m = fmaxf(m, __int_as_float(__builtin_amdgcn_ds_swizzle(__float_as_int(m), 0x041F))); // ^1
    return m;
}

__device__ __forceinline__ float bperm32(float x, int axor32) {
    return __int_as_float(
        __builtin_amdgcn_ds_bpermute(axor32, __float_as_int(x)));
}

__device__ __forceinline__ void gather(float v[8], const float* __restrict__ img,
                                       const int voff[8], int lane, int x) {
    if (x >= PT && x <= WW - 1 - (KK - 1 - PT)) {      // interior: x in [10,212]
        const float* base = img + (x - PT) * CHN;      // wave-uniform base
#pragma unroll
        for (int i = 0; i < 8; ++i) v[i] = base[voff[i]];
    } else {
#pragma unroll
        for (int i = 0; i < 8; ++i) {
            int s   = i * 64 + lane;
            int se  = min(s, AREA - 1);
            int row = se / KK;
            int col = se - row * KK;
            int gy672 = voff[i] - col * CHN;
            int gx = reflect224(x - PT + col);
            v[i] = img[gy672 + gx * CHN];
        }
    }
    v[7] = (lane < AREA - 448) ? v[7] : INFF;          // slots >= 484 -> +INF
}

__global__ __launch_bounds__(256)
void median_blend_kernel(const float* __restrict__ in,
                         const float* __restrict__ blend,
                         float* __restrict__ out) {
    const int lane = threadIdx.x & 63;
    const int wid  = threadIdx.x >> 6;
    const int wg = blockIdx.x * 4 + wid;        // wave-uniform group id
    // wg = ((b*CHN + c)*HH + y)*XGS + xg
    const int xg = wg % XGS;
    const int t1 = wg / XGS;
    const int y  = t1 % HH;
    const int t2 = t1 / HH;
    const int c  = t2 % CHN;
    const int b  = t2 / CHN;

    const float f = blend[0];
    const float* img  = in  + (size_t)b * (HH * WW * CHN) + c;
    float*       outp = out + (size_t)b * (HH * WW * CHN) + c;

    // per-wave lane constants: voff = gy*672 + col*3 (vertical reflect baked in)
    int voff[8];
#pragma unroll
    for (int i = 0; i < 8; ++i) {
        int s   = i * 64 + lane;
        int se  = min(s, AREA - 1);
        int row = se / KK;
        int col = se - row * KK;
        int gy  = reflect224(y - PT + row);
        voff[i] = gy * (WW * CHN) + col * CHN;
    }

    const int axor32 = (lane ^ 32) << 2;        // hoisted bpermute byte addr
    const float ninf = NINFF;
    const float NINV = -1.0f / (float)AREA;     // Newton slope: -1/484

    const int x0 = xg * PXW;
    float tprev = 0.5f;

#pragma unroll 1
    for (int j = 0; j < PXW; j += 2) {
        const int xA = x0 + j;
        const int xB = xA + 1;

        float vA[8], vB[8];
        gather(vA, img, voff, lane, xA);
        gather(vB, img, voff, lane, xB);

        // ---- warm-started Newton probes to |d| <= DT, pair in lockstep ----
        float tA = tprev, tB = tprev;
        int CA = count8(vA, tA);
        int CB = count8(vB, tB);
        int dA = CA - RANK, dB = CB - RANK;
        float loA = 0.0f, hiA = 1.0f, loB = 0.0f, hiB = 1.0f;
        bool actA = (dA > DT || dA < -DT), actB = (dB > DT || dB < -DT);
#pragma unroll 1
        for (int it = 0; it < 20 && (actA || actB); ++it) {
            if (actA) {
                if (dA > 0) hiA = tA; else loA = tA;
                float tn = fmaf((float)dA, NINV, tA);
                if (!(tn > loA && tn < hiA)) tn = 0.5f * (loA + hiA);
                if (!(tn > loA && tn < hiA)) actA = false;   // degenerate (tie)
                else {
                    tA = tn;
                    CA = count8(vA, tA);
                    dA = CA - RANK;
                    actA = (dA > DT || dA < -DT);
                }
            }
            if (actB) {
                if (dB > 0) hiB = tB; else loB = tB;
                float tn = fmaf((float)dB, NINV, tB);
                if (!(tn > loB && tn < hiB)) tn = 0.5f * (loB + hiB);
                if (!(tn > loB && tn < hiB)) actB = false;   // degenerate (tie)
                else {
                    tB = tn;
                    CB = count8(vB, tB);
                    dB = CB - RANK;
                    actB = (dB > DT || dB < -DT);
                }
            }
        }

        // ---- pair-packed q-counting sign-folded max-peel ----
        // top side (d>=0): need (d+1)-th largest of {v<t}    -> peel max of v
        // bottom side    : need (-d)-th smallest of {v>=t}   -> peel max of -v
        const bool topA = (dA >= 0), topB = (dB >= 0);
        int eA = topA ? dA + 1 : -dA;
        int eB = topB ? dB + 1 : -dB;
        const int sgnA = topA ? 0 : (int)0x80000000;
        const int sgnB = topB ? 0 : (int)0x80000000;
        if (topA) {                               // fold in place (wave-uniform branch)
#pragma unroll
            for (int i = 0; i < 8; ++i) vA[i] = (vA[i] < tA) ? vA[i] : ninf;
        } else {
#pragma unroll
            for (int i = 0; i < 8; ++i) vA[i] = (vA[i] < tA) ? ninf : -vA[i];
        }
        if (topB) {
#pragma unroll
            for (int i = 0; i < 8; ++i) vB[i] = (vB[i] < tB) ? vB[i] : ninf;
        } else {
#pragma unroll
            for (int i = 0; i < 8; ++i) vB[i] = (vB[i] < tB) ? ninf : -vB[i];
        }
        // (+INF sentinels: top -> excluded; bottom -> fold to -INF, never
        //  selected since e <= #real candidates.)

        float medA = tA, medB = tB;               // provably overwritten
        bool doneA = false, doneB = false;
#pragma unroll 1
        for (int r = 0; r < 300 && !(doneA && doneB); ++r) {
            float pA = doneA ? ninf : tree8(vA);
            float pB = doneB ? ninf : tree8(vB);
            pA = fmaxf(pA, bperm32(pA, axor32));  // halves now symmetric
            pB = fmaxf(pB, bperm32(pB, axor32));
            float m = (lane < 32) ? pA : pB;      // pack A|B, one shared reduce
            m = half_bfly(m);
            const float mA = __int_as_float(
                __builtin_amdgcn_readlane(__float_as_int(m), 0));
            const float mB = __int_as_float(
                __builtin_amdgcn_readlane(__float_as_int(m), 32));
            if (!doneA) {
                int q = 0;
#pragma unroll
                for (int i = 0; i < 8; ++i)
                    q += __popcll(__ballot(vA[i] == mA));
                if (eA <= q) {
                    medA = __int_as_float(__float_as_int(mA) ^ sgnA);
                    doneA = true;
                } else {
                    eA -= q;
#pragma unroll
                    for (int i = 0; i < 8; ++i)
                        vA[i] = (vA[i] == mA) ? ninf : vA[i];
                }
            }
            if (!doneB) {
                int q = 0;
#pragma unroll
                for (int i = 0; i < 8; ++i)
                    q += __popcll(__ballot(vB[i] == mB));
                if (eB <= q) {
                    medB = __int_as_float(__float_as_int(mB) ^ sgnB);
                    doneB = true;
                } else {
                    eB -= q;
#pragma unroll
                    for (int i = 0; i < 8; ++i)
                        vB[i] = (vB[i] == mB) ? ninf : vB[i];
                }
            }
        }
        tprev = medB;                              // warm start for next pair

        // ---- blend + store ----
        const float xcA = img[y * (WW * CHN) + xA * CHN];
        const float xcB = img[y * (WW * CHN) + xB * CHN];
        if (lane == 0) {
            outp[y * (WW * CHN) + xA * CHN] = medA + f * (xcA - medA);
            outp[y * (WW * CHN) + xB * CHN] = medB + f * (xcB - medB);
        }
    }
}

extern "C" void kernel_launch(void* const* d_in, const int* in_sizes, int n_in,
                              void* d_out, int out_size, void* d_ws, size_t ws_size,
                              hipStream_t stream) {
    const float* in    = (const float*)d_in[0];
    const float* blend = (const float*)d_in[1];
    float* out = (float*)d_out;

    const int nwaves  = 2 * CHN * HH * XGS;   // 37632
    const int nblocks = nwaves / 4;           // 9408
    median_blend_kernel<<<nblocks, 256, 0, stream>>>(in, blend, out);
}